// Round 3
// baseline (68861.340 us; speedup 1.0000x reference)
//
#include <hip/hip_runtime.h>

#define H    50
#define T    65536
#define NTHREADS 448

// ws layout (floats) — logical dense layouts (LDS padding is applied at LDS
// level only; weight registers are sliced per 16 logical columns).
#define WC1_OFF 0        // 200*64
#define WC2_OFF 12800    // 200*128
#define BC1_OFF 38400    // 200
#define BC2_OFF 38600    // 200

// Prep: permute rows (orig r = gate*50+j  ->  new r' = j*4+gate) and pad cols.
// Wc1: 200 x 64  : cols 0..6 = W_ih1[:,0:7], col 7 = W_ih1[:,7] (err), 8..57 = W_hh1, 58..63 = 0
// Wc2: 200 x 128 : cols 0..49 = W_ih2, 50..99 = W_hh2, 100..127 = 0
__global__ void prep_kernel(const float* __restrict__ Wih1, const float* __restrict__ Whh1,
                            const float* __restrict__ bih1, const float* __restrict__ bhh1,
                            const float* __restrict__ Wih2, const float* __restrict__ Whh2,
                            const float* __restrict__ bih2, const float* __restrict__ bhh2,
                            float* __restrict__ ws) {
  int idx = blockIdx.x * blockDim.x + threadIdx.x;
  if (idx < 200 * 64) {
    int nr = idx >> 6, c = idx & 63;
    int j = nr >> 2, gate = nr & 3, r = gate * 50 + j;
    float v = 0.f;
    if (c < 8) v = Wih1[r * 8 + c];
    else if (c < 58) v = Whh1[r * 50 + (c - 8)];
    ws[WC1_OFF + idx] = v;
  }
  if (idx < 200 * 128) {
    int nr = idx >> 7, c = idx & 127;
    int j = nr >> 2, gate = nr & 3, r = gate * 50 + j;
    float v = 0.f;
    if (c < 50) v = Wih2[r * 50 + c];
    else if (c < 100) v = Whh2[r * 50 + (c - 50)];
    ws[WC2_OFF + idx] = v;
  }
  if (idx < 200) {
    int j = idx >> 2, gate = idx & 3, r = gate * 50 + j;
    ws[BC1_OFF + idx] = bih1[r] + bhh1[r];
    ws[BC2_OFF + idx] = bih2[r] + bhh2[r];
  }
}

__device__ __forceinline__ float sigm(float x) {
  return __builtin_amdgcn_rcpf(1.f + __expf(-x));
}
__device__ __forceinline__ float tanh_(float x) {
  return 1.f - 2.f * __builtin_amdgcn_rcpf(1.f + __expf(2.f * x));
}
// LDS-only barrier: no vmcnt drain, so global prefetch loads and y-stores
// pipeline across steps. "memory" clobber pins LDS op ordering at IR level.
__device__ __forceinline__ void bar() {
  asm volatile("s_waitcnt lgkmcnt(0)\n\ts_barrier" ::: "memory");
}

// DPP cross-lane add: x + x[lane ^ pattern], VALU pipe (no LDS latency).
// 0xB1 = quad_perm(1,0,3,2) = xor1 ; 0x4E = quad_perm(2,3,0,1) = xor2
// 0x141 = row_half_mirror (8-lane complete after xor1+xor2)
// 0x140 = row_mirror (16-lane complete)
template<int CTRL>
__device__ __forceinline__ float dpp_add(float x) {
  int y = __builtin_amdgcn_mov_dpp(__float_as_int(x), CTRL, 0xF, 0xF, true);
  return x + __int_as_float(y);
}

// logical column -> padded LDS offset: chunks of 16 floats at stride 20
// (80 B, 16 B-aligned; chunk bank starts {0,20,8,28,16,4,24,12} - disjoint)
__device__ __forceinline__ int phys(int c) { return (c >> 4) * 20 + (c & 15); }

// NOTE: no lambda for the step body — a by-reference lambda capture takes the
// address of wa1/wa2, which (if not inlined) blocks SROA and forces the weight
// arrays into scratch (R2: VGPR_Count=88, FETCH_SIZE=1292MB of per-step
// scratch reload traffic). Body is written once inline with runtime parity.
__launch_bounds__(NTHREADS, 2)
__global__ void lstm_kernel(const float* __restrict__ xseq,
                            const float* __restrict__ ws,
                            const float* __restrict__ Wout,
                            const float* __restrict__ bout,
                            float* __restrict__ out) {
  // Double-buffered (parity = t&1) step-state in LDS, chunk-padded (16->20).
  // AIN logical [0..6]=x_t [7]=err(t-1) [8..57]=h1(t-1) [58..63]=0   (4 chunks)
  // CIN logical [0..49]=h1(t) [50..99]=h2(t-1) [100..127]=0          (8 chunks)
  __shared__ __align__(16) float AIN[2][80];
  __shared__ __align__(16) float CIN[2][160];
  __shared__ float ACT[2];

  const int tid = threadIdx.x;
  const float* Wc1 = ws + WC1_OFF;
  const float* Wc2 = ws + WC2_OFF;
  const float* bc1 = ws + BC1_OFF;
  const float* bc2 = ws + BC2_OFF;

  // zero all LDS (pads must stay 0 forever; poison could be NaN)
  for (int i = tid; i < 2 * 80; i += NTHREADS) ((float*)AIN)[i] = 0.f;
  for (int i = tid; i < 2 * 160; i += NTHREADS) ((float*)CIN)[i] = 0.f;
  if (tid < 2) ACT[tid] = 0.f;

  const int g  = tid >> 2, p  = tid & 3;  // phase A: unit g, 16-col slice p (tid<200)
  const int g2 = tid >> 3, p2 = tid & 7;  // phase C: unit g2, 16-col slice p2 (tid<400)

  float wa1[4][16]; float b1[4];
  float wa2[4][16]; float b2[4];
  float c1 = 0.f, c2 = 0.f, err = 0.f, xr = 0.f, wo = 0.f, bo = 0.f;

  if (tid < 200) {
    #pragma unroll
    for (int k = 0; k < 4; k++) {
      const float4* src = (const float4*)&Wc1[(4 * g + k) * 64 + p * 16];
      #pragma unroll
      for (int q = 0; q < 4; q++) {
        float4 v = src[q];
        wa1[k][4*q+0] = v.x; wa1[k][4*q+1] = v.y; wa1[k][4*q+2] = v.z; wa1[k][4*q+3] = v.w;
      }
      b1[k] = bc1[4 * g + k];
    }
  }
  if (tid < 400) {
    #pragma unroll
    for (int k = 0; k < 4; k++) {
      const float4* src = (const float4*)&Wc2[(4 * g2 + k) * 128 + p2 * 16];
      #pragma unroll
      for (int q = 0; q < 4; q++) {
        float4 v = src[q];
        wa2[k][4*q+0] = v.x; wa2[k][4*q+1] = v.y; wa2[k][4*q+2] = v.z; wa2[k][4*q+3] = v.w;
      }
      b2[k] = bc2[4 * g2 + k];
    }
  }
  const int yoff = phys(50 + tid);   // phase-Y read slot (cols >99 never written -> 0)
  if (tid < 64) {
    wo = (tid < 50) ? Wout[tid] : 0.f;
    bo = bout[0];
  }
  // loader lanes: prefetch x rows two steps ahead (depth-2 pipeline)
  if (tid >= 400 && tid < 408) {
    int c = tid - 400;
    float v0 = xseq[c];             // row 0
    if (c < 7) AIN[0][c] = v0; else ACT[0] = v0;
    xr = xseq[8 + c];               // row 1 staged in regs
  }
  __syncthreads();

  for (int t = 0; t < T; ++t) {
    const int par = t & 1;
    float* ain  = AIN[par];
    float* ainN = AIN[par ^ 1];
    float* cin  = CIN[par];
    float* cinN = CIN[par ^ 1];

    // ---------------- Phase A: cell-1 gates + h1/c1 update ----------------
    if (tid < 200) {
      float ur[16];
      const float4* up = (const float4*)&ain[p * 20];
      #pragma unroll
      for (int q = 0; q < 4; q++) {
        float4 v = up[q];
        ur[4*q+0] = v.x; ur[4*q+1] = v.y; ur[4*q+2] = v.z; ur[4*q+3] = v.w;
      }
      float a0 = 0.f, a1 = 0.f, a2 = 0.f, a3 = 0.f;
      #pragma unroll
      for (int j = 0; j < 16; j++) {
        a0 += wa1[0][j] * ur[j];
        a1 += wa1[1][j] * ur[j];
        a2 += wa1[2][j] * ur[j];
        a3 += wa1[3][j] * ur[j];
      }
      a0 = dpp_add<0xB1>(a0); a0 = dpp_add<0x4E>(a0);
      a1 = dpp_add<0xB1>(a1); a1 = dpp_add<0x4E>(a1);
      a2 = dpp_add<0xB1>(a2); a2 = dpp_add<0x4E>(a2);
      a3 = dpp_add<0xB1>(a3); a3 = dpp_add<0x4E>(a3);
      if (p == 0) {  // this lane owns unit g: rows 4g+{0,1,2,3} = i,f,g,o
        float gi = sigm (a0 + b1[0]);
        float gf = sigm (a1 + b1[1]);
        float gg = tanh_(a2 + b1[2]);
        float go = sigm (a3 + b1[3]);
        c1 = gf * c1 + gi * gg;
        float h1 = go * tanh_(c1);
        cin[phys(g)]       = h1;  // for cell-2 this step
        ainN[phys(8 + g)]  = h1;  // for cell-1 next step
      }
    }
    bar();
    // ---------------- Phase C: cell-2 gates + h2/c2 update + loader -------
    if (tid < 400) {
      float ur[16];
      const float4* up = (const float4*)&cin[p2 * 20];
      #pragma unroll
      for (int q = 0; q < 4; q++) {
        float4 v = up[q];
        ur[4*q+0] = v.x; ur[4*q+1] = v.y; ur[4*q+2] = v.z; ur[4*q+3] = v.w;
      }
      float a0 = 0.f, a1 = 0.f, a2 = 0.f, a3 = 0.f;
      #pragma unroll
      for (int j = 0; j < 16; j++) {
        a0 += wa2[0][j] * ur[j];
        a1 += wa2[1][j] * ur[j];
        a2 += wa2[2][j] * ur[j];
        a3 += wa2[3][j] * ur[j];
      }
      a0 = dpp_add<0xB1>(a0); a0 = dpp_add<0x4E>(a0); a0 = dpp_add<0x141>(a0);
      a1 = dpp_add<0xB1>(a1); a1 = dpp_add<0x4E>(a1); a1 = dpp_add<0x141>(a1);
      a2 = dpp_add<0xB1>(a2); a2 = dpp_add<0x4E>(a2); a2 = dpp_add<0x141>(a2);
      a3 = dpp_add<0xB1>(a3); a3 = dpp_add<0x4E>(a3); a3 = dpp_add<0x141>(a3);
      if (p2 == 0) {  // owns unit g2
        float gi = sigm (a0 + b2[0]);
        float gf = sigm (a1 + b2[1]);
        float gg = tanh_(a2 + b2[2]);
        float go = sigm (a3 + b2[3]);
        c2 = gf * c2 + gi * gg;
        float h2 = go * tanh_(c2);
        cinN[phys(50 + g2)] = h2;  // for y(t) and cell-2 next step
      }
    } else if (tid < 408) {
      int c = tid - 400;
      if (c < 7) ainN[c] = xr; else ACT[par ^ 1] = xr;  // publish x(t+1)
      int nt = (t + 2 < T) ? t + 2 : T - 1;
      xr = xseq[nt * 8 + c];                            // fetch x(t+2)
    }
    bar();
    // ---------------- Phase Y: y, out store, err update (wave 0) ----------
    if (tid < 64) {
      float v = cinN[yoff] * wo;   // wo=0 for lanes >=50; pad slots stay 0
      v = dpp_add<0xB1>(v); v = dpp_add<0x4E>(v);
      v = dpp_add<0x141>(v); v = dpp_add<0x140>(v);
      v = v + __int_as_float(__builtin_amdgcn_ds_swizzle(__float_as_int(v), 0x401F)); // xor16
      float vlo = __int_as_float(__builtin_amdgcn_readlane(__float_as_int(v), 0));
      float vhi = __int_as_float(__builtin_amdgcn_readlane(__float_as_int(v), 32));
      if (tid == 0) {
        float y = vlo + vhi + bo;
        out[t] = y;                       // fire-and-forget (no vmcnt drain at bar)
        err = 0.9f * err + 0.1f * (ACT[par] - y);
        ainN[7] = err;
      }
    }
    bar();
  }
}

extern "C" void kernel_launch(void* const* d_in, const int* in_sizes, int n_in,
                              void* d_out, int out_size, void* d_ws, size_t ws_size,
                              hipStream_t stream) {
  const float* xseq = (const float*)d_in[0];
  const float* Wih1 = (const float*)d_in[1];
  const float* Whh1 = (const float*)d_in[2];
  const float* bih1 = (const float*)d_in[3];
  const float* bhh1 = (const float*)d_in[4];
  const float* Wih2 = (const float*)d_in[5];
  const float* Whh2 = (const float*)d_in[6];
  const float* bih2 = (const float*)d_in[7];
  const float* bhh2 = (const float*)d_in[8];
  const float* Wout = (const float*)d_in[9];
  const float* bout = (const float*)d_in[10];
  float* ws = (float*)d_ws;

  prep_kernel<<<100, 256, 0, stream>>>(Wih1, Whh1, bih1, bhh1,
                                       Wih2, Whh2, bih2, bhh2, ws);
  lstm_kernel<<<1, NTHREADS, 0, stream>>>(xseq, ws, Wout, bout, (float*)d_out);
}

// Round 4
// 68686.237 us; speedup vs baseline: 1.0025x; 1.0025x over previous
//
#include <hip/hip_runtime.h>

#define H    50
#define T    65536
#define NTHREADS 448

// ws layout (floats)
#define WC1_OFF 0        // 200*64
#define WC2_OFF 12800    // 200*128
#define BC1_OFF 38400    // 200
#define BC2_OFF 38600    // 200

// Prep: permute rows (orig r = gate*50+j  ->  new r' = j*4+gate) and pad cols.
// Wc1: 200 x 64  : cols 0..6 = W_ih1[:,0:7], col 7 = W_ih1[:,7] (err), 8..57 = W_hh1, 58..63 = 0
// Wc2: 200 x 128 : cols 0..49 = W_ih2, 50..99 = W_hh2, 100..127 = 0
__global__ void prep_kernel(const float* __restrict__ Wih1, const float* __restrict__ Whh1,
                            const float* __restrict__ bih1, const float* __restrict__ bhh1,
                            const float* __restrict__ Wih2, const float* __restrict__ Whh2,
                            const float* __restrict__ bih2, const float* __restrict__ bhh2,
                            float* __restrict__ ws) {
  int idx = blockIdx.x * blockDim.x + threadIdx.x;
  if (idx < 200 * 64) {
    int nr = idx >> 6, c = idx & 63;
    int j = nr >> 2, gate = nr & 3, r = gate * 50 + j;
    float v = 0.f;
    if (c < 8) v = Wih1[r * 8 + c];
    else if (c < 58) v = Whh1[r * 50 + (c - 8)];
    ws[WC1_OFF + idx] = v;
  }
  if (idx < 200 * 128) {
    int nr = idx >> 7, c = idx & 127;
    int j = nr >> 2, gate = nr & 3, r = gate * 50 + j;
    float v = 0.f;
    if (c < 50) v = Wih2[r * 50 + c];
    else if (c < 100) v = Whh2[r * 50 + (c - 50)];
    ws[WC2_OFF + idx] = v;
  }
  if (idx < 200) {
    int j = idx >> 2, gate = idx & 3, r = gate * 50 + j;
    ws[BC1_OFF + idx] = bih1[r] + bhh1[r];
    ws[BC2_OFF + idx] = bih2[r] + bhh2[r];
  }
}

__device__ __forceinline__ float sigm(float x) {
  return __builtin_amdgcn_rcpf(1.f + __expf(-x));
}
__device__ __forceinline__ float tanh_(float x) {
  return 1.f - 2.f * __builtin_amdgcn_rcpf(1.f + __expf(2.f * x));
}
// LDS-only barrier: no vmcnt drain, so global prefetch loads and y-stores
// pipeline across steps. "memory" clobber pins LDS op ordering at IR level.
__device__ __forceinline__ void bar() {
  asm volatile("s_waitcnt lgkmcnt(0)\n\ts_barrier" ::: "memory");
}

// DPP cross-lane add: x + x[lane ^ pattern], VALU pipe (no LDS latency).
template<int CTRL>
__device__ __forceinline__ float dpp_add(float x) {
  int y = __builtin_amdgcn_mov_dpp(__float_as_int(x), CTRL, 0xF, 0xF, true);
  return x + __int_as_float(y);
}

// logical column -> padded LDS offset: chunks of 16 floats at stride 20
// (80 B, 16 B-aligned; chunk bank starts {0,20,8,28,16,4,24,12} - disjoint)
__device__ __forceinline__ int phys(int c) { return (c >> 4) * 20 + (c & 15); }

// SSA vector type for a 16-col weight slice. NO per-thread arrays anywhere:
// R1-R3 showed the compiler leaves float[4][16] allocas in scratch
// (VGPR_Count=88, FETCH_SIZE=1.29GB of per-step reload traffic). ext_vector
// values are first-class SSA — they can only be VGPRs.
typedef float f16v __attribute__((ext_vector_type(16)));

// one quarter (4 cols) of a 16-col dot product; Q and U are literal
#define MACQ(A, W, Q, U) \
  A += W[4*(Q)+0] * (U).x; \
  A += W[4*(Q)+1] * (U).y; \
  A += W[4*(Q)+2] * (U).z; \
  A += W[4*(Q)+3] * (U).w;

#define DOT16(A, W, U0, U1, U2, U3) \
  MACQ(A, W, 0, U0) MACQ(A, W, 1, U1) MACQ(A, W, 2, U2) MACQ(A, W, 3, U3)

__launch_bounds__(NTHREADS, 2)   // 7 waves/block; VGPR budget 256
__global__ void lstm_kernel(const float* __restrict__ xseq,
                            const float* __restrict__ ws,
                            const float* __restrict__ Wout,
                            const float* __restrict__ bout,
                            float* __restrict__ out) {
  // Double-buffered (parity = t&1) step-state in LDS, chunk-padded (16->20).
  // AIN logical [0..6]=x_t [7]=err(t-1) [8..57]=h1(t-1) [58..63]=0   (4 chunks)
  // CIN logical [0..49]=h1(t) [50..99]=h2(t-1) [100..127]=0          (8 chunks)
  __shared__ __align__(16) float AIN[2][80];
  __shared__ __align__(16) float CIN[2][160];
  __shared__ float ACT[2];

  const int tid = threadIdx.x;
  const float* Wc1 = ws + WC1_OFF;
  const float* Wc2 = ws + WC2_OFF;

  // zero all LDS (pads must stay 0 forever; poison could be NaN)
  for (int i = tid; i < 2 * 80; i += NTHREADS) ((float*)AIN)[i] = 0.f;
  for (int i = tid; i < 2 * 160; i += NTHREADS) ((float*)CIN)[i] = 0.f;
  if (tid < 2) ACT[tid] = 0.f;

  const int g  = tid >> 2, p  = tid & 3;  // phase A: unit g, 16-col slice p (tid<200)
  const int g2 = tid >> 3, p2 = tid & 7;  // phase C: unit g2, 16-col slice p2 (tid<400)
  const int gc  = (g  < 50) ? g  : 49;    // clamped: weights defined for ALL threads
  const int g2c = (g2 < 50) ? g2 : 49;    // (no divergence-dependent liveness)

  // ---- persistent weight registers (SSA vectors, unconditional init) ----
  // Wc1 row byte offset = (4g+k)*256 + p*64 -> 64B aligned for f16v loads.
  f16v wa10 = *(const f16v*)(Wc1 + (4 * gc + 0) * 64 + p * 16);
  f16v wa11 = *(const f16v*)(Wc1 + (4 * gc + 1) * 64 + p * 16);
  f16v wa12 = *(const f16v*)(Wc1 + (4 * gc + 2) * 64 + p * 16);
  f16v wa13 = *(const f16v*)(Wc1 + (4 * gc + 3) * 64 + p * 16);
  f16v wa20 = *(const f16v*)(Wc2 + (4 * g2c + 0) * 128 + p2 * 16);
  f16v wa21 = *(const f16v*)(Wc2 + (4 * g2c + 1) * 128 + p2 * 16);
  f16v wa22 = *(const f16v*)(Wc2 + (4 * g2c + 2) * 128 + p2 * 16);
  f16v wa23 = *(const f16v*)(Wc2 + (4 * g2c + 3) * 128 + p2 * 16);
  float4 b1 = *(const float4*)(ws + BC1_OFF + 4 * gc);
  float4 b2 = *(const float4*)(ws + BC2_OFF + 4 * g2c);

  float c1 = 0.f, c2 = 0.f, err = 0.f, xr = 0.f;
  const float wo = (tid < 50) ? Wout[tid] : 0.f;
  const float bo = bout[0];
  const int yoff = phys(50 + (tid & 63));  // phase-Y slot (cols>99 stay 0)

  // loader lanes: prefetch x rows two steps ahead (depth-2 pipeline)
  if (tid >= 400 && tid < 408) {
    int c = tid - 400;
    float v0 = xseq[c];             // row 0
    if (c < 7) AIN[0][c] = v0; else ACT[0] = v0;
    xr = xseq[8 + c];               // row 1 staged in regs
  }
  __syncthreads();

  for (int t = 0; t < T; ++t) {
    const int par = t & 1;
    float* ain  = AIN[par];
    float* ainN = AIN[par ^ 1];
    float* cin  = CIN[par];
    float* cinN = CIN[par ^ 1];

    // ---------------- Phase A: cell-1 gates + h1/c1 update ----------------
    if (tid < 200) {
      const float4* up = (const float4*)&ain[p * 20];
      float4 u0 = up[0], u1 = up[1], u2 = up[2], u3 = up[3];
      float a0 = 0.f, a1 = 0.f, a2 = 0.f, a3 = 0.f;
      DOT16(a0, wa10, u0, u1, u2, u3)
      DOT16(a1, wa11, u0, u1, u2, u3)
      DOT16(a2, wa12, u0, u1, u2, u3)
      DOT16(a3, wa13, u0, u1, u2, u3)
      a0 = dpp_add<0xB1>(a0); a0 = dpp_add<0x4E>(a0);
      a1 = dpp_add<0xB1>(a1); a1 = dpp_add<0x4E>(a1);
      a2 = dpp_add<0xB1>(a2); a2 = dpp_add<0x4E>(a2);
      a3 = dpp_add<0xB1>(a3); a3 = dpp_add<0x4E>(a3);
      if (p == 0) {  // this lane owns unit g: rows 4g+{0,1,2,3} = i,f,g,o
        float gi = sigm (a0 + b1.x);
        float gf = sigm (a1 + b1.y);
        float gg = tanh_(a2 + b1.z);
        float go = sigm (a3 + b1.w);
        c1 = gf * c1 + gi * gg;
        float h1 = go * tanh_(c1);
        cin[phys(g)]       = h1;  // for cell-2 this step
        ainN[phys(8 + g)]  = h1;  // for cell-1 next step
      }
    }
    bar();
    // ---------------- Phase C: cell-2 gates + h2/c2 update + loader -------
    if (tid < 400) {
      const float4* up = (const float4*)&cin[p2 * 20];
      float4 u0 = up[0], u1 = up[1], u2 = up[2], u3 = up[3];
      float a0 = 0.f, a1 = 0.f, a2 = 0.f, a3 = 0.f;
      DOT16(a0, wa20, u0, u1, u2, u3)
      DOT16(a1, wa21, u0, u1, u2, u3)
      DOT16(a2, wa22, u0, u1, u2, u3)
      DOT16(a3, wa23, u0, u1, u2, u3)
      a0 = dpp_add<0xB1>(a0); a0 = dpp_add<0x4E>(a0); a0 = dpp_add<0x141>(a0);
      a1 = dpp_add<0xB1>(a1); a1 = dpp_add<0x4E>(a1); a1 = dpp_add<0x141>(a1);
      a2 = dpp_add<0xB1>(a2); a2 = dpp_add<0x4E>(a2); a2 = dpp_add<0x141>(a2);
      a3 = dpp_add<0xB1>(a3); a3 = dpp_add<0x4E>(a3); a3 = dpp_add<0x141>(a3);
      if (p2 == 0) {  // owns unit g2
        float gi = sigm (a0 + b2.x);
        float gf = sigm (a1 + b2.y);
        float gg = tanh_(a2 + b2.z);
        float go = sigm (a3 + b2.w);
        c2 = gf * c2 + gi * gg;
        float h2 = go * tanh_(c2);
        cinN[phys(50 + g2)] = h2;  // for y(t) and cell-2 next step
      }
    } else if (tid < 408) {
      int c = tid - 400;
      if (c < 7) ainN[c] = xr; else ACT[par ^ 1] = xr;  // publish x(t+1)
      int nt = (t + 2 < T) ? t + 2 : T - 1;
      xr = xseq[nt * 8 + c];                            // fetch x(t+2)
    }
    bar();
    // ---------------- Phase Y: y, out store, err update (wave 0) ----------
    if (tid < 64) {
      float v = cinN[yoff] * wo;   // wo=0 for lanes >=50; pad slots stay 0
      v = dpp_add<0xB1>(v); v = dpp_add<0x4E>(v);
      v = dpp_add<0x141>(v); v = dpp_add<0x140>(v);
      v = v + __int_as_float(__builtin_amdgcn_ds_swizzle(__float_as_int(v), 0x401F)); // xor16
      float vlo = __int_as_float(__builtin_amdgcn_readlane(__float_as_int(v), 0));
      float vhi = __int_as_float(__builtin_amdgcn_readlane(__float_as_int(v), 32));
      if (tid == 0) {
        float y = vlo + vhi + bo;
        out[t] = y;                       // fire-and-forget (no vmcnt drain at bar)
        err = 0.9f * err + 0.1f * (ACT[par] - y);
        ainN[7] = err;
      }
    }
    bar();
  }
}

extern "C" void kernel_launch(void* const* d_in, const int* in_sizes, int n_in,
                              void* d_out, int out_size, void* d_ws, size_t ws_size,
                              hipStream_t stream) {
  const float* xseq = (const float*)d_in[0];
  const float* Wih1 = (const float*)d_in[1];
  const float* Whh1 = (const float*)d_in[2];
  const float* bih1 = (const float*)d_in[3];
  const float* bhh1 = (const float*)d_in[4];
  const float* Wih2 = (const float*)d_in[5];
  const float* Whh2 = (const float*)d_in[6];
  const float* bih2 = (const float*)d_in[7];
  const float* bhh2 = (const float*)d_in[8];
  const float* Wout = (const float*)d_in[9];
  const float* bout = (const float*)d_in[10];
  float* ws = (float*)d_ws;

  prep_kernel<<<100, 256, 0, stream>>>(Wih1, Whh1, bih1, bhh1,
                                       Wih2, Whh2, bih2, bhh2, ws);
  lstm_kernel<<<1, NTHREADS, 0, stream>>>(xseq, ws, Wout, bout, (float*)d_out);
}

// Round 5
// 67670.679 us; speedup vs baseline: 1.0176x; 1.0150x over previous
//
#include <hip/hip_runtime.h>

#define H    50
#define T    65536
#define NTHREADS 704

// ws layout (floats)
#define WC1_OFF 0        // 200*64
#define WC2_OFF 12800    // 200*128
#define BC1_OFF 38400    // 200
#define BC2_OFF 38600    // 200

// Prep: permute rows (orig r = gate*50+j  ->  new r' = j*4+gate) and pad cols.
// Wc1: 200 x 64  : cols 0..6 = W_ih1[:,0:7], col 7 = W_ih1[:,7] (err), 8..57 = W_hh1, 58..63 = 0
// Wc2: 200 x 128 : cols 0..49 = W_ih2, 50..99 = W_hh2, 100..127 = 0
__global__ void prep_kernel(const float* __restrict__ Wih1, const float* __restrict__ Whh1,
                            const float* __restrict__ bih1, const float* __restrict__ bhh1,
                            const float* __restrict__ Wih2, const float* __restrict__ Whh2,
                            const float* __restrict__ bih2, const float* __restrict__ bhh2,
                            float* __restrict__ ws) {
  int idx = blockIdx.x * blockDim.x + threadIdx.x;
  if (idx < 200 * 64) {
    int nr = idx >> 6, c = idx & 63;
    int j = nr >> 2, gate = nr & 3, r = gate * 50 + j;
    float v = 0.f;
    if (c < 8) v = Wih1[r * 8 + c];
    else if (c < 58) v = Whh1[r * 50 + (c - 8)];
    ws[WC1_OFF + idx] = v;
  }
  if (idx < 200 * 128) {
    int nr = idx >> 7, c = idx & 127;
    int j = nr >> 2, gate = nr & 3, r = gate * 50 + j;
    float v = 0.f;
    if (c < 50) v = Wih2[r * 50 + c];
    else if (c < 100) v = Whh2[r * 50 + (c - 50)];
    ws[WC2_OFF + idx] = v;
  }
  if (idx < 200) {
    int j = idx >> 2, gate = idx & 3, r = gate * 50 + j;
    ws[BC1_OFF + idx] = bih1[r] + bhh1[r];
    ws[BC2_OFF + idx] = bih2[r] + bhh2[r];
  }
}

__device__ __forceinline__ float sigm(float x) {
  return __builtin_amdgcn_rcpf(1.f + __expf(-x));
}
__device__ __forceinline__ float tanh_(float x) {
  return 1.f - 2.f * __builtin_amdgcn_rcpf(1.f + __expf(2.f * x));
}
// LDS-only barrier: no vmcnt drain, so global prefetch loads and y-stores
// pipeline across steps.
__device__ __forceinline__ void bar() {
  asm volatile("s_waitcnt lgkmcnt(0)\n\ts_barrier" ::: "memory");
}

// DPP cross-lane add: x + x[lane ^ pattern], VALU pipe.
template<int CTRL>
__device__ __forceinline__ float dpp_add(float x) {
  int y = __builtin_amdgcn_mov_dpp(__float_as_int(x), CTRL, 0xF, 0xF, true);
  return x + __int_as_float(y);
}

// logical column -> padded LDS offset: chunks of 16 floats at stride 20
// (80 B, 16 B-aligned; chunk bank starts {0,20,8,28,16,4,24,12} - disjoint)
__device__ __forceinline__ int phys(int c) { return (c >> 4) * 20 + (c & 15); }

typedef float f16v __attribute__((ext_vector_type(16)));

// Pin a value to a VGPR via an opaque no-op asm def. Inline-asm results are
// NEVER rematerializable, so the scheduler cannot sink the feeding loads back
// into the loop (R2-R4: occupancy-chasing remat re-executed all weight loads
// every step -> VGPR_Count=88, FETCH_SIZE=1.29GB, ~20KB/step on the serial
// dependency chain).
#define PINF(x) asm volatile("" : "+v"(x))
__device__ __forceinline__ void pin16(f16v& w) {
  #pragma unroll
  for (int i = 0; i < 16; i++) { float t = w[i]; PINF(t); w[i] = t; }
}

#define MACQ(A, W, Q, U) \
  A += W[4*(Q)+0] * (U).x; \
  A += W[4*(Q)+1] * (U).y; \
  A += W[4*(Q)+2] * (U).z; \
  A += W[4*(Q)+3] * (U).w;

#define DOT16(A, W, U0, U1, U2, U3) \
  MACQ(A, W, 0, U0) MACQ(A, W, 1, U1) MACQ(A, W, 2, U2) MACQ(A, W, 3, U3)

// Thread map (704 = 11 waves):
//   tids   0..199  : cell-1  (unit g = tid>>2, slice p = tid&3)      [waves 0-3]
//   tids 256..655  : cell-2  (u=tid-256, unit g2=u>>3, slice p2=u&7) [waves 4-10]
//   tids 656..663  : x loaders
//   tids   0..63   : phase-Y reduction (wave 0)
// Cell-1 and cell-2 use the SAME w0..w3/bb registers (disjoint threads,
// wave-aligned split) -> per-thread weight demand 64 floats, not 128.
__launch_bounds__(NTHREADS, 2)
__global__ void lstm_kernel(const float* __restrict__ xseq,
                            const float* __restrict__ ws,
                            const float* __restrict__ Wout,
                            const float* __restrict__ bout,
                            float* __restrict__ out) {
  // Double-buffered (parity = t&1) step-state in LDS, chunk-padded (16->20).
  // AIN logical [0..6]=x_t [7]=err(t-1) [8..57]=h1(t-1) [58..63]=0   (4 chunks)
  // CIN logical [0..49]=h1(t) [50..99]=h2(t-1) [100..127]=0          (8 chunks)
  __shared__ __align__(16) float AIN[2][80];
  __shared__ __align__(16) float CIN[2][160];
  __shared__ float ACT[2];

  const int tid = threadIdx.x;
  const float* Wc1 = ws + WC1_OFF;
  const float* Wc2 = ws + WC2_OFF;

  // zero all LDS (pads must stay 0 forever; poison could be NaN)
  for (int i = tid; i < 2 * 80; i += NTHREADS) ((float*)AIN)[i] = 0.f;
  for (int i = tid; i < 2 * 160; i += NTHREADS) ((float*)CIN)[i] = 0.f;
  if (tid < 2) ACT[tid] = 0.f;

  const int g  = tid >> 2,        p  = tid & 3;        // cell-1 map
  const int u2 = tid - 256;
  const int g2 = u2 >> 3,         p2 = u2 & 7;         // cell-2 map
  const bool isC1 = (tid < 200);
  const bool isC2 = (tid >= 256 && tid < 656);
  const bool isLd = (tid >= 656 && tid < 664);

  // ---- persistent shared weight registers (one set per thread) ----
  f16v w0 = 0.f, w1 = 0.f, w2 = 0.f, w3 = 0.f;
  float4 bb = {0.f, 0.f, 0.f, 0.f};
  if (isC1) {
    w0 = *(const f16v*)(Wc1 + (4 * g + 0) * 64 + p * 16);
    w1 = *(const f16v*)(Wc1 + (4 * g + 1) * 64 + p * 16);
    w2 = *(const f16v*)(Wc1 + (4 * g + 2) * 64 + p * 16);
    w3 = *(const f16v*)(Wc1 + (4 * g + 3) * 64 + p * 16);
    bb = *(const float4*)(ws + BC1_OFF + 4 * g);
  } else if (isC2) {
    w0 = *(const f16v*)(Wc2 + (4 * g2 + 0) * 128 + p2 * 16);
    w1 = *(const f16v*)(Wc2 + (4 * g2 + 1) * 128 + p2 * 16);
    w2 = *(const f16v*)(Wc2 + (4 * g2 + 2) * 128 + p2 * 16);
    w3 = *(const f16v*)(Wc2 + (4 * g2 + 3) * 128 + p2 * 16);
    bb = *(const float4*)(ws + BC2_OFF + 4 * g2);
  }
  pin16(w0); pin16(w1); pin16(w2); pin16(w3);
  PINF(bb.x); PINF(bb.y); PINF(bb.z); PINF(bb.w);

  float c1 = 0.f, c2 = 0.f, err = 0.f, xr = 0.f;
  const float wo = (tid < 50) ? Wout[tid] : 0.f;
  const float bo = bout[0];
  const int yoff = phys(50 + (tid & 63));  // phase-Y slot (cols>99 stay 0)

  // loader lanes: prefetch x rows two steps ahead (depth-2 pipeline)
  if (isLd) {
    int c = tid - 656;
    float v0 = xseq[c];             // row 0
    if (c < 7) AIN[0][c] = v0; else ACT[0] = v0;
    xr = xseq[8 + c];               // row 1 staged in regs
  }
  __syncthreads();

  for (int t = 0; t < T; ++t) {
    const int par = t & 1;
    float* ain  = AIN[par];
    float* ainN = AIN[par ^ 1];
    float* cin  = CIN[par];
    float* cinN = CIN[par ^ 1];

    // ---------------- Phase A: cell-1 gates + h1/c1 update ----------------
    if (isC1) {
      const float4* up = (const float4*)&ain[p * 20];
      float4 u0 = up[0], u1 = up[1], u2v = up[2], u3 = up[3];
      float a0 = 0.f, a1 = 0.f, a2 = 0.f, a3 = 0.f;
      DOT16(a0, w0, u0, u1, u2v, u3)
      DOT16(a1, w1, u0, u1, u2v, u3)
      DOT16(a2, w2, u0, u1, u2v, u3)
      DOT16(a3, w3, u0, u1, u2v, u3)
      a0 = dpp_add<0xB1>(a0); a0 = dpp_add<0x4E>(a0);
      a1 = dpp_add<0xB1>(a1); a1 = dpp_add<0x4E>(a1);
      a2 = dpp_add<0xB1>(a2); a2 = dpp_add<0x4E>(a2);
      a3 = dpp_add<0xB1>(a3); a3 = dpp_add<0x4E>(a3);
      if (p == 0) {  // lane owns unit g (rows 4g+{0,1,2,3} = i,f,g,o)
        float gi = sigm (a0 + bb.x);
        float gf = sigm (a1 + bb.y);
        float gg = tanh_(a2 + bb.z);
        float go = sigm (a3 + bb.w);
        c1 = gf * c1 + gi * gg;
        float h1 = go * tanh_(c1);
        cin[phys(g)]       = h1;  // for cell-2 this step
        ainN[phys(8 + g)]  = h1;  // for cell-1 next step
      }
    }
    bar();
    // ---------------- Phase C: cell-2 gates + h2/c2 update + loader -------
    if (isC2) {
      const float4* up = (const float4*)&cin[p2 * 20];
      float4 u0 = up[0], u1 = up[1], u2v = up[2], u3 = up[3];
      float a0 = 0.f, a1 = 0.f, a2 = 0.f, a3 = 0.f;
      DOT16(a0, w0, u0, u1, u2v, u3)
      DOT16(a1, w1, u0, u1, u2v, u3)
      DOT16(a2, w2, u0, u1, u2v, u3)
      DOT16(a3, w3, u0, u1, u2v, u3)
      a0 = dpp_add<0xB1>(a0); a0 = dpp_add<0x4E>(a0); a0 = dpp_add<0x141>(a0);
      a1 = dpp_add<0xB1>(a1); a1 = dpp_add<0x4E>(a1); a1 = dpp_add<0x141>(a1);
      a2 = dpp_add<0xB1>(a2); a2 = dpp_add<0x4E>(a2); a2 = dpp_add<0x141>(a2);
      a3 = dpp_add<0xB1>(a3); a3 = dpp_add<0x4E>(a3); a3 = dpp_add<0x141>(a3);
      if (p2 == 0) {  // owns unit g2
        float gi = sigm (a0 + bb.x);
        float gf = sigm (a1 + bb.y);
        float gg = tanh_(a2 + bb.z);
        float go = sigm (a3 + bb.w);
        c2 = gf * c2 + gi * gg;
        float h2 = go * tanh_(c2);
        cinN[phys(50 + g2)] = h2;  // for y(t) and cell-2 next step
      }
    } else if (isLd) {
      int c = tid - 656;
      if (c < 7) ainN[c] = xr; else ACT[par ^ 1] = xr;  // publish x(t+1)
      int nt = (t + 2 < T) ? t + 2 : T - 1;
      xr = xseq[nt * 8 + c];                            // fetch x(t+2)
    }
    bar();
    // ---------------- Phase Y: y, out store, err update (wave 0) ----------
    if (tid < 64) {
      float v = cinN[yoff] * wo;   // wo=0 for lanes >=50; pad slots stay 0
      v = dpp_add<0xB1>(v); v = dpp_add<0x4E>(v);
      v = dpp_add<0x141>(v); v = dpp_add<0x140>(v);
      v = v + __int_as_float(__builtin_amdgcn_ds_swizzle(__float_as_int(v), 0x401F)); // xor16
      float vlo = __int_as_float(__builtin_amdgcn_readlane(__float_as_int(v), 0));
      float vhi = __int_as_float(__builtin_amdgcn_readlane(__float_as_int(v), 32));
      if (tid == 0) {
        float y = vlo + vhi + bo;
        out[t] = y;                       // fire-and-forget
        err = 0.9f * err + 0.1f * (ACT[par] - y);
        ainN[7] = err;
      }
    }
    bar();
  }
}

extern "C" void kernel_launch(void* const* d_in, const int* in_sizes, int n_in,
                              void* d_out, int out_size, void* d_ws, size_t ws_size,
                              hipStream_t stream) {
  const float* xseq = (const float*)d_in[0];
  const float* Wih1 = (const float*)d_in[1];
  const float* Whh1 = (const float*)d_in[2];
  const float* bih1 = (const float*)d_in[3];
  const float* bhh1 = (const float*)d_in[4];
  const float* Wih2 = (const float*)d_in[5];
  const float* Whh2 = (const float*)d_in[6];
  const float* bih2 = (const float*)d_in[7];
  const float* bhh2 = (const float*)d_in[8];
  const float* Wout = (const float*)d_in[9];
  const float* bout = (const float*)d_in[10];
  float* ws = (float*)d_ws;

  prep_kernel<<<100, 256, 0, stream>>>(Wih1, Whh1, bih1, bhh1,
                                       Wih2, Whh2, bih2, bhh2, ws);
  lstm_kernel<<<1, NTHREADS, 0, stream>>>(xseq, ws, Wout, bout, (float*)d_out);
}

// Round 6
// 67647.089 us; speedup vs baseline: 1.0179x; 1.0003x over previous
//
#include <hip/hip_runtime.h>

#define H    50
#define T    65536
#define NTHREADS 704

// ws layout (floats)
#define WC1_OFF 0        // 200*64
#define WC2_OFF 12800    // 200*128
#define BC1_OFF 38400    // 200
#define BC2_OFF 38600    // 200

// Prep: permute rows (orig r = gate*50+j  ->  new r' = j*4+gate) and pad cols.
// Wc1: 200 x 64  : cols 0..6 = W_ih1[:,0:7], col 7 = W_ih1[:,7] (err), 8..57 = W_hh1, 58..63 = 0
// Wc2: 200 x 128 : cols 0..49 = W_ih2, 50..99 = W_hh2, 100..127 = 0
__global__ void prep_kernel(const float* __restrict__ Wih1, const float* __restrict__ Whh1,
                            const float* __restrict__ bih1, const float* __restrict__ bhh1,
                            const float* __restrict__ Wih2, const float* __restrict__ Whh2,
                            const float* __restrict__ bih2, const float* __restrict__ bhh2,
                            float* __restrict__ ws) {
  int idx = blockIdx.x * blockDim.x + threadIdx.x;
  if (idx < 200 * 64) {
    int nr = idx >> 6, c = idx & 63;
    int j = nr >> 2, gate = nr & 3, r = gate * 50 + j;
    float v = 0.f;
    if (c < 8) v = Wih1[r * 8 + c];
    else if (c < 58) v = Whh1[r * 50 + (c - 8)];
    ws[WC1_OFF + idx] = v;
  }
  if (idx < 200 * 128) {
    int nr = idx >> 7, c = idx & 127;
    int j = nr >> 2, gate = nr & 3, r = gate * 50 + j;
    float v = 0.f;
    if (c < 50) v = Wih2[r * 50 + c];
    else if (c < 100) v = Whh2[r * 50 + (c - 50)];
    ws[WC2_OFF + idx] = v;
  }
  if (idx < 200) {
    int j = idx >> 2, gate = idx & 3, r = gate * 50 + j;
    ws[BC1_OFF + idx] = bih1[r] + bhh1[r];
    ws[BC2_OFF + idx] = bih2[r] + bhh2[r];
  }
}

__device__ __forceinline__ float sigm(float x) {
  return __builtin_amdgcn_rcpf(1.f + __expf(-x));
}
__device__ __forceinline__ float tanh_(float x) {
  return 1.f - 2.f * __builtin_amdgcn_rcpf(1.f + __expf(2.f * x));
}
// LDS-only barrier: no vmcnt drain, so global prefetch loads and y-stores
// pipeline across steps.
__device__ __forceinline__ void bar() {
  asm volatile("s_waitcnt lgkmcnt(0)\n\ts_barrier" ::: "memory");
}

// DPP cross-lane add: x + x[lane ^ pattern], VALU pipe.
template<int CTRL>
__device__ __forceinline__ float dpp_add(float x) {
  int y = __builtin_amdgcn_mov_dpp(__float_as_int(x), CTRL, 0xF, 0xF, true);
  return x + __int_as_float(y);
}

// logical column -> padded LDS offset: chunks of 16 floats at stride 20
// (80 B, 16 B-aligned; chunk bank starts {0,20,8,28,16,4,24,12} - disjoint)
__device__ __forceinline__ int phys(int c) { return (c >> 4) * 20 + (c & 15); }

typedef float f16v __attribute__((ext_vector_type(16)));

// Pin a value to a VGPR via an opaque no-op asm def (blocks remat-sinking of
// the weight loads into the loop). R5 showed pins alone aren't enough: the
// occupancy-chasing allocator then SPILLS the pinned values (VGPR=56). The
// amdgpu_waves_per_eu(3,3) attribute below is the companion fix.
#define PINF(x) asm volatile("" : "+v"(x))
__device__ __forceinline__ void pin16(f16v& w) {
  #pragma unroll
  for (int i = 0; i < 16; i++) { float t = w[i]; PINF(t); w[i] = t; }
}

#define MACQ(A, W, Q, U) \
  A += W[4*(Q)+0] * (U).x; \
  A += W[4*(Q)+1] * (U).y; \
  A += W[4*(Q)+2] * (U).z; \
  A += W[4*(Q)+3] * (U).w;

#define DOT16(A, W, U0, U1, U2, U3) \
  MACQ(A, W, 0, U0) MACQ(A, W, 1, U1) MACQ(A, W, 2, U2) MACQ(A, W, 3, U3)

// Thread map (704 = 11 waves):
//   tids   0..199  : cell-1  (unit g = tid>>2, slice p = tid&3)      [waves 0-3]
//   tids 256..655  : cell-2  (u=tid-256, unit g2=u>>3, slice p2=u&7) [waves 4-10]
//   tids 656..663  : x loaders
//   tids   0..63   : phase-Y reduction (wave 0)
// Cell-1 and cell-2 use the SAME w0..w3/bb registers (disjoint threads,
// wave-aligned split) -> per-thread weight demand 64 floats, not 128.
//
// amdgpu_waves_per_eu(3,3): THE fix for R2-R5. launch_bounds' 2nd arg sets
// only the MIN waves/EU; with no max the backend chases occupancy (irrelevant
// for our single-block launch) down to VGPR=56, spilling all weights to
// scratch and reloading ~150KB/step on the serial chain. min=max=3 gives a
// 512/3=168-VGPR budget and removes the incentive to shrink below it.
// 11 waves / 4 SIMDs needs 3 waves on the busiest SIMD: 168 VGPRs fits 3/EU.
__global__ void
__launch_bounds__(NTHREADS)
__attribute__((amdgpu_waves_per_eu(3, 3)))
lstm_kernel(const float* __restrict__ xseq,
            const float* __restrict__ ws,
            const float* __restrict__ Wout,
            const float* __restrict__ bout,
            float* __restrict__ out) {
  // Double-buffered (parity = t&1) step-state in LDS, chunk-padded (16->20).
  // AIN logical [0..6]=x_t [7]=err(t-1) [8..57]=h1(t-1) [58..63]=0   (4 chunks)
  // CIN logical [0..49]=h1(t) [50..99]=h2(t-1) [100..127]=0          (8 chunks)
  __shared__ __align__(16) float AIN[2][80];
  __shared__ __align__(16) float CIN[2][160];
  __shared__ float ACT[2];

  const int tid = threadIdx.x;
  const float* Wc1 = ws + WC1_OFF;
  const float* Wc2 = ws + WC2_OFF;

  // zero all LDS (pads must stay 0 forever; poison could be NaN)
  for (int i = tid; i < 2 * 80; i += NTHREADS) ((float*)AIN)[i] = 0.f;
  for (int i = tid; i < 2 * 160; i += NTHREADS) ((float*)CIN)[i] = 0.f;
  if (tid < 2) ACT[tid] = 0.f;

  const int g  = tid >> 2,        p  = tid & 3;        // cell-1 map
  const int u2 = tid - 256;
  const int g2 = u2 >> 3,         p2 = u2 & 7;         // cell-2 map
  const bool isC1 = (tid < 200);
  const bool isC2 = (tid >= 256 && tid < 656);
  const bool isLd = (tid >= 656 && tid < 664);

  // ---- persistent shared weight registers (one set per thread) ----
  f16v w0 = 0.f, w1 = 0.f, w2 = 0.f, w3 = 0.f;
  float4 bb = {0.f, 0.f, 0.f, 0.f};
  if (isC1) {
    w0 = *(const f16v*)(Wc1 + (4 * g + 0) * 64 + p * 16);
    w1 = *(const f16v*)(Wc1 + (4 * g + 1) * 64 + p * 16);
    w2 = *(const f16v*)(Wc1 + (4 * g + 2) * 64 + p * 16);
    w3 = *(const f16v*)(Wc1 + (4 * g + 3) * 64 + p * 16);
    bb = *(const float4*)(ws + BC1_OFF + 4 * g);
  } else if (isC2) {
    w0 = *(const f16v*)(Wc2 + (4 * g2 + 0) * 128 + p2 * 16);
    w1 = *(const f16v*)(Wc2 + (4 * g2 + 1) * 128 + p2 * 16);
    w2 = *(const f16v*)(Wc2 + (4 * g2 + 2) * 128 + p2 * 16);
    w3 = *(const f16v*)(Wc2 + (4 * g2 + 3) * 128 + p2 * 16);
    bb = *(const float4*)(ws + BC2_OFF + 4 * g2);
  }
  pin16(w0); pin16(w1); pin16(w2); pin16(w3);
  PINF(bb.x); PINF(bb.y); PINF(bb.z); PINF(bb.w);

  float c1 = 0.f, c2 = 0.f, err = 0.f, xr = 0.f;
  const float wo = (tid < 50) ? Wout[tid] : 0.f;
  const float bo = bout[0];
  const int yoff = phys(50 + (tid & 63));  // phase-Y slot (cols>99 stay 0)

  // loader lanes: prefetch x rows two steps ahead (depth-2 pipeline)
  if (isLd) {
    int c = tid - 656;
    float v0 = xseq[c];             // row 0
    if (c < 7) AIN[0][c] = v0; else ACT[0] = v0;
    xr = xseq[8 + c];               // row 1 staged in regs
  }
  __syncthreads();

  for (int t = 0; t < T; ++t) {
    const int par = t & 1;
    float* ain  = AIN[par];
    float* ainN = AIN[par ^ 1];
    float* cin  = CIN[par];
    float* cinN = CIN[par ^ 1];

    // ---------------- Phase A: cell-1 gates + h1/c1 update ----------------
    if (isC1) {
      const float4* up = (const float4*)&ain[p * 20];
      float4 u0 = up[0], u1 = up[1], u2v = up[2], u3 = up[3];
      float a0 = 0.f, a1 = 0.f, a2 = 0.f, a3 = 0.f;
      DOT16(a0, w0, u0, u1, u2v, u3)
      DOT16(a1, w1, u0, u1, u2v, u3)
      DOT16(a2, w2, u0, u1, u2v, u3)
      DOT16(a3, w3, u0, u1, u2v, u3)
      a0 = dpp_add<0xB1>(a0); a0 = dpp_add<0x4E>(a0);
      a1 = dpp_add<0xB1>(a1); a1 = dpp_add<0x4E>(a1);
      a2 = dpp_add<0xB1>(a2); a2 = dpp_add<0x4E>(a2);
      a3 = dpp_add<0xB1>(a3); a3 = dpp_add<0x4E>(a3);
      if (p == 0) {  // lane owns unit g (rows 4g+{0,1,2,3} = i,f,g,o)
        float gi = sigm (a0 + bb.x);
        float gf = sigm (a1 + bb.y);
        float gg = tanh_(a2 + bb.z);
        float go = sigm (a3 + bb.w);
        c1 = gf * c1 + gi * gg;
        float h1 = go * tanh_(c1);
        cin[phys(g)]       = h1;  // for cell-2 this step
        ainN[phys(8 + g)]  = h1;  // for cell-1 next step
      }
    }
    bar();
    // ---------------- Phase C: cell-2 gates + h2/c2 update + loader -------
    if (isC2) {
      const float4* up = (const float4*)&cin[p2 * 20];
      float4 u0 = up[0], u1 = up[1], u2v = up[2], u3 = up[3];
      float a0 = 0.f, a1 = 0.f, a2 = 0.f, a3 = 0.f;
      DOT16(a0, w0, u0, u1, u2v, u3)
      DOT16(a1, w1, u0, u1, u2v, u3)
      DOT16(a2, w2, u0, u1, u2v, u3)
      DOT16(a3, w3, u0, u1, u2v, u3)
      a0 = dpp_add<0xB1>(a0); a0 = dpp_add<0x4E>(a0); a0 = dpp_add<0x141>(a0);
      a1 = dpp_add<0xB1>(a1); a1 = dpp_add<0x4E>(a1); a1 = dpp_add<0x141>(a1);
      a2 = dpp_add<0xB1>(a2); a2 = dpp_add<0x4E>(a2); a2 = dpp_add<0x141>(a2);
      a3 = dpp_add<0xB1>(a3); a3 = dpp_add<0x4E>(a3); a3 = dpp_add<0x141>(a3);
      if (p2 == 0) {  // owns unit g2
        float gi = sigm (a0 + bb.x);
        float gf = sigm (a1 + bb.y);
        float gg = tanh_(a2 + bb.z);
        float go = sigm (a3 + bb.w);
        c2 = gf * c2 + gi * gg;
        float h2 = go * tanh_(c2);
        cinN[phys(50 + g2)] = h2;  // for y(t) and cell-2 next step
      }
    } else if (isLd) {
      int c = tid - 656;
      if (c < 7) ainN[c] = xr; else ACT[par ^ 1] = xr;  // publish x(t+1)
      int nt = (t + 2 < T) ? t + 2 : T - 1;
      xr = xseq[nt * 8 + c];                            // fetch x(t+2)
    }
    bar();
    // ---------------- Phase Y: y, out store, err update (wave 0) ----------
    if (tid < 64) {
      float v = cinN[yoff] * wo;   // wo=0 for lanes >=50; pad slots stay 0
      v = dpp_add<0xB1>(v); v = dpp_add<0x4E>(v);
      v = dpp_add<0x141>(v); v = dpp_add<0x140>(v);
      v = v + __int_as_float(__builtin_amdgcn_ds_swizzle(__float_as_int(v), 0x401F)); // xor16
      float vlo = __int_as_float(__builtin_amdgcn_readlane(__float_as_int(v), 0));
      float vhi = __int_as_float(__builtin_amdgcn_readlane(__float_as_int(v), 32));
      if (tid == 0) {
        float y = vlo + vhi + bo;
        out[t] = y;                       // fire-and-forget
        err = 0.9f * err + 0.1f * (ACT[par] - y);
        ainN[7] = err;
      }
    }
    bar();
  }
}

extern "C" void kernel_launch(void* const* d_in, const int* in_sizes, int n_in,
                              void* d_out, int out_size, void* d_ws, size_t ws_size,
                              hipStream_t stream) {
  const float* xseq = (const float*)d_in[0];
  const float* Wih1 = (const float*)d_in[1];
  const float* Whh1 = (const float*)d_in[2];
  const float* bih1 = (const float*)d_in[3];
  const float* bhh1 = (const float*)d_in[4];
  const float* Wih2 = (const float*)d_in[5];
  const float* Whh2 = (const float*)d_in[6];
  const float* bih2 = (const float*)d_in[7];
  const float* bhh2 = (const float*)d_in[8];
  const float* Wout = (const float*)d_in[9];
  const float* bout = (const float*)d_in[10];
  float* ws = (float*)d_ws;

  prep_kernel<<<100, 256, 0, stream>>>(Wih1, Whh1, bih1, bhh1,
                                       Wih2, Whh2, bih2, bhh2, ws);
  lstm_kernel<<<1, NTHREADS, 0, stream>>>(xseq, ws, Wout, bout, (float*)d_out);
}